// Round 9
// baseline (278.001 us; speedup 1.0000x reference)
//
#include <hip/hip_runtime.h>
#include <hip/hip_fp16.h>

#define D 128
#define SCAN_B 256

typedef __attribute__((ext_vector_type(8))) _Float16 f16x8;
typedef __attribute__((ext_vector_type(4))) float f32x4;

typedef __attribute__((address_space(1))) const void gas_t;
typedef __attribute__((address_space(3))) void las_t;

// ---- hierarchical exclusive scan ----
__global__ void scan_pass1(const int* __restrict__ cnt, int* __restrict__ rs,
                           int* __restrict__ bsum, int N) {
    __shared__ int lds[SCAN_B];
    int tid = threadIdx.x;
    int i = blockIdx.x * SCAN_B + tid;
    int v = (i < N) ? cnt[i] : 0;
    lds[tid] = v;
    __syncthreads();
    for (int o = 1; o < SCAN_B; o <<= 1) {
        int t = (tid >= o) ? lds[tid - o] : 0;
        __syncthreads();
        lds[tid] += t;
        __syncthreads();
    }
    if (i < N) rs[i] = lds[tid] - v;
    if (tid == SCAN_B - 1) bsum[blockIdx.x] = lds[tid];
}

__global__ void scan_pass2(int* __restrict__ bsum, int nb) {
    __shared__ int lds[SCAN_B];
    int tid = threadIdx.x;
    int v = (tid < nb) ? bsum[tid] : 0;
    lds[tid] = v;
    __syncthreads();
    for (int o = 1; o < SCAN_B; o <<= 1) {
        int t = (tid >= o) ? lds[tid - o] : 0;
        __syncthreads();
        lds[tid] += t;
        __syncthreads();
    }
    if (tid < nb) bsum[tid] = lds[tid] - v;
}

__global__ void scan_pass3(int* __restrict__ rs, int* __restrict__ cursor,
                           const int* __restrict__ bsum, const int* __restrict__ cnt,
                           float* __restrict__ inv, int N) {
    int i = blockIdx.x * SCAN_B + threadIdx.x;
    if (i < N) {
        int v = rs[i] + bsum[blockIdx.x];
        rs[i] = v;
        cursor[i] = v;
        inv[i] = 1.0f / (float)max(cnt[i], 1);
    }
}

__global__ void fill_kernel(const int* __restrict__ ei, int E,
                            int* __restrict__ cursor, int* __restrict__ csr) {
    int e = blockIdx.x * blockDim.x + threadIdx.x;
    if (e < E) {
        int src = ei[e], dst = ei[E + e];
        int pos = atomicAdd(&cursor[dst], 1);
        csr[pos] = src;
    }
}

// ---- fused prologue: weight pack | fp32->f16 hi/lo cvt | degree count ----
__global__ void prologue_kernel(const float* __restrict__ W1l, const float* __restrict__ W1r,
                                const float* __restrict__ W2l, const float* __restrict__ W2r,
                                const float* __restrict__ Wf, unsigned short* __restrict__ pw,
                                const float* __restrict__ x, __half* __restrict__ xh,
                                __half* __restrict__ xl, int n8,
                                const int* __restrict__ ei, int E, int* __restrict__ cnt) {
    int t = blockIdx.x * blockDim.x + threadIdx.x;
    if (t < 10240) {
        int idx = t;
        int w = idx >> 11;
        int r = idx & 2047;
        int ks = r >> 9;
        int tt = (r >> 6) & 7;
        int lane = r & 63;
        int q = lane >> 4, n = lane & 15;
        const float* W = (w == 0) ? W1l : (w == 1) ? W1r : (w == 2) ? W2l : (w == 3) ? W2r : Wf;
        unsigned short* dh = pw + (size_t)w * 32768;
        unsigned short* dl = dh + 16384;
        int off = ((ks * 8 + tt) * 64 + lane) * 8;
#pragma unroll
        for (int j = 0; j < 8; j++) {
            float v = W[(size_t)(ks * 32 + q * 8 + j) * D + tt * 16 + n];
            __half hb = __float2half_rn(v);
            dh[off + j] = __half_as_ushort(hb);
            dl[off + j] = __half_as_ushort(__float2half_rn(v - __half2float(hb)));
        }
    } else if (t < 10240 + n8) {
        int i = t - 10240;
        const float4* x4 = (const float4*)x;
        float4 a = x4[2 * i], b = x4[2 * i + 1];
        float v[8] = {a.x, a.y, a.z, a.w, b.x, b.y, b.z, b.w};
        uint4 oh, ol;
        __half2* ph = (__half2*)&oh;
        __half2* pl = (__half2*)&ol;
#pragma unroll
        for (int jj = 0; jj < 4; jj++) {
            __half h0 = __float2half_rn(v[2 * jj]);
            __half h1 = __float2half_rn(v[2 * jj + 1]);
            ph[jj] = __halves2half2(h0, h1);
            pl[jj] = __halves2half2(__float2half_rn(v[2 * jj] - __half2float(h0)),
                                    __float2half_rn(v[2 * jj + 1] - __half2float(h1)));
        }
        ((uint4*)xh)[i] = oh;
        ((uint4*)xl)[i] = ol;
    } else {
        int e = t - 10240 - n8;
        if (e < E) atomicAdd(&cnt[ei[E + e]], 1);
    }
}

__device__ __forceinline__ void acc8(uint4 v, float* s) {
    const __half2* h = reinterpret_cast<const __half2*>(&v);
    float2 f0 = __half22float2(h[0]);
    float2 f1 = __half22float2(h[1]);
    float2 f2 = __half22float2(h[2]);
    float2 f3 = __half22float2(h[3]);
    s[0] += f0.x; s[1] += f0.y; s[2] += f1.x; s[3] += f1.y;
    s[4] += f2.x; s[5] += f2.y; s[6] += f3.x; s[7] += f3.y;
}

__device__ __forceinline__ void split_f16(const float* v, uint4& hi, uint4& lo) {
    __half2* ph = (__half2*)&hi;
    __half2* pl = (__half2*)&lo;
#pragma unroll
    for (int jj = 0; jj < 4; jj++) {
        __half h0 = __float2half_rn(v[2 * jj]);
        __half h1 = __float2half_rn(v[2 * jj + 1]);
        ph[jj] = __halves2half2(h0, h1);
        pl[jj] = __halves2half2(__float2half_rn(v[2 * jj] - __half2float(h0)),
                                __float2half_rn(v[2 * jj + 1] - __half2float(h1)));
    }
}

// ---- fused cooperative-gather + full-row-wave MFMA GEMM ----
// block = 4 waves x 16 rows = 64 rows. grid = ceil(N/64). K=256 (agg | x-or-h).
// Gather: 16 lanes per node (coalesced 256B row reads, same shape as the standalone
// aggregate); result redistributed to MFMA fragment layout via a wave-private 8 KB
// XOR-swizzled LDS tile (explicit barrier between write and read phases).
// Weights then staged via global_load_lds double-buffer into the SAME 32 KB region.
template <int LAYER>
__global__ __launch_bounds__(256) void fused_gemm(
        const int* __restrict__ csr, const int* __restrict__ rs,
        const int* __restrict__ cnt, const float* __restrict__ inv,
        const uint4* __restrict__ Gsrc,                                // gather rows (hi)
        const uint4* __restrict__ Ah1, const uint4* __restrict__ Al1,  // x or h1 (root side)
        const uint4* __restrict__ W0h, const uint4* __restrict__ W0l,
        const uint4* __restrict__ W1h, const uint4* __restrict__ W1l,
        const float* __restrict__ bias,
        const uint4* __restrict__ W2h, const uint4* __restrict__ W2l,
        const float* __restrict__ bias2,
        float* out, __half* Hout, int N) {
    __shared__ uint4 smem4[2048];   // 32 KB: agg staging -> W double-buffer -> FC H staging
    const int GS = (LAYER == 1) ? 16 : 32;   // gather row stride in uint4

    const int tid = threadIdx.x;
    const int lane = tid & 63;
    const int wave = tid >> 6;
    const int c = lane & 15;
    const int q = lane >> 4;
    const int R = blockIdx.x * 64 + wave * 16;
    const int row0 = min(R + c, N - 1);
    const size_t rbA1 = (size_t)row0 * GS + q;

#define STAGE_W(ks_, b_)                                                                   \
    do {                                                                                   \
        const uint4* sh_ = (((ks_) < 4) ? W0h : W1h) + (size_t)((ks_) & 3) * 512;          \
        const uint4* sl_ = (((ks_) < 4) ? W0l : W1l) + (size_t)((ks_) & 3) * 512;          \
        const uint4* s_ = ((wave < 2) ? sh_ : sl_) + ((wave & 1) * 256 + lane);            \
        uint4* d_ = smem4 + (b_) * 1024 + (wave >> 1) * 512 + (wave & 1) * 256;            \
        __builtin_amdgcn_global_load_lds((gas_t*)(s_), (las_t*)(d_), 16, 0, 0);            \
        __builtin_amdgcn_global_load_lds((gas_t*)(s_ + 64), (las_t*)(d_ + 64), 16, 0, 0);  \
        __builtin_amdgcn_global_load_lds((gas_t*)(s_ + 128), (las_t*)(d_ + 128), 16, 0, 0);\
        __builtin_amdgcn_global_load_lds((gas_t*)(s_ + 192), (las_t*)(d_ + 192), 16, 0, 0);\
    } while (0)

    // root-side A frags issued first; latency hides under the gather
    uint4 Xs_h[4], Xs_l[4];
#pragma unroll
    for (int kl = 0; kl < 4; kl++) {
        Xs_h[kl] = Ah1[rbA1 + kl * 4];
        Xs_l[kl] = Al1[rbA1 + kl * 4];
    }

    // ---- cooperative gather: 16-lane group g handles rows g*4+rr (rr=0..3) ----
    // lane cg of the group reads uint4 col cg of each neighbor row (256B coalesced).
    uint4* aw = smem4 + wave * 512;   // wave-private 8 KB agg tile
    {
        const int g = lane >> 4;
        const int cg = lane & 15;
#pragma unroll
        for (int rr = 0; rr < 4; rr++) {
            int rl = g * 4 + rr;
            int node = min(R + rl, N - 1);
            int deg = cnt[node];
            int st = rs[node];
            float iv = inv[node];
            float s[8] = {0.f, 0.f, 0.f, 0.f, 0.f, 0.f, 0.f, 0.f};
            int i = 0;
            for (; i + 4 <= deg; i += 4) {
                int n0 = csr[st + i + 0], n1 = csr[st + i + 1];
                int n2 = csr[st + i + 2], n3 = csr[st + i + 3];
                uint4 v0 = Gsrc[(size_t)n0 * GS + cg];
                uint4 v1 = Gsrc[(size_t)n1 * GS + cg];
                uint4 v2 = Gsrc[(size_t)n2 * GS + cg];
                uint4 v3 = Gsrc[(size_t)n3 * GS + cg];
                acc8(v0, s); acc8(v1, s); acc8(v2, s); acc8(v3, s);
            }
            for (; i < deg; i++) {
                int n0 = csr[st + i];
                uint4 v0 = Gsrc[(size_t)n0 * GS + cg];
                acc8(v0, s);
            }
            float v[8];
#pragma unroll
            for (int j = 0; j < 8; j++) v[j] = s[j] * iv;
            uint4 hi, lo;
            split_f16(v, hi, lo);
            int sidx = rl * 32 + (cg ^ (rl & 7));   // XOR swizzle: write side conflict-free
            aw[sidx] = hi;
            aw[sidx + 16] = lo;
        }
    }
    __syncthreads();   // agg writes visible (defensive: cross-lane RAW made explicit)

    uint4 Agg_h[4], Agg_l[4];
#pragma unroll
    for (int ks = 0; ks < 4; ks++) {
        int ridx = c * 32 + ((ks * 4 + q) ^ (c & 7));
        Agg_h[ks] = aw[ridx];
        Agg_l[ks] = aw[ridx + 16];
    }
    __syncthreads();   // all waves done with agg tiles before W staging overwrites LDS

    STAGE_W(0, 0);
    STAGE_W(1, 1);
    asm volatile("s_waitcnt vmcnt(0)" ::: "memory");
    __syncthreads();

    f32x4 acc[8];
#pragma unroll
    for (int t = 0; t < 8; t++)
#pragma unroll
        for (int r = 0; r < 4; r++) acc[t][r] = 0.0f;

#pragma unroll
    for (int ks = 0; ks < 8; ks++) {
        const int b = ks & 1;
        const uint4* wb = smem4 + b * 1024;
        f16x8 ah = __builtin_bit_cast(f16x8, (ks < 4) ? Agg_h[ks & 3] : Xs_h[ks & 3]);
        f16x8 al = __builtin_bit_cast(f16x8, (ks < 4) ? Agg_l[ks & 3] : Xs_l[ks & 3]);
#pragma unroll
        for (int t = 0; t < 8; t++) {
            f16x8 bh = __builtin_bit_cast(f16x8, wb[t * 64 + lane]);
            f16x8 bl = __builtin_bit_cast(f16x8, wb[512 + t * 64 + lane]);
            acc[t] = __builtin_amdgcn_mfma_f32_16x16x32_f16(ah, bh, acc[t], 0, 0, 0);
            acc[t] = __builtin_amdgcn_mfma_f32_16x16x32_f16(al, bh, acc[t], 0, 0, 0);
            acc[t] = __builtin_amdgcn_mfma_f32_16x16x32_f16(ah, bl, acc[t], 0, 0, 0);
        }
        if (ks < 7) {
            asm volatile("s_waitcnt vmcnt(0)" ::: "memory");
            __syncthreads();
            if (ks < 6) STAGE_W(ks + 2, b);   // overwrite just-consumed buffer
        }
    }

    // bias + row L2-norm (whole row in this wave: 16-lane shfl reduce) + relu
#pragma unroll
    for (int t = 0; t < 8; t++) {
        float bv = bias[t * 16 + c];
#pragma unroll
        for (int r = 0; r < 4; r++) acc[t][r] += bv;
    }
#pragma unroll
    for (int r = 0; r < 4; r++) {
        float v = 0.0f;
#pragma unroll
        for (int t = 0; t < 8; t++) v += acc[t][r] * acc[t][r];
        v += __shfl_xor(v, 1, 16);
        v += __shfl_xor(v, 2, 16);
        v += __shfl_xor(v, 4, 16);
        v += __shfl_xor(v, 8, 16);
        float rn = 1.0f / fmaxf(sqrtf(v), 1e-12f);
#pragma unroll
        for (int t = 0; t < 8; t++) acc[t][r] = fmaxf(acc[t][r] * rn, 0.0f);
    }

    if (LAYER == 1) {
        // write h1 row-interleaved (hi 128 | lo 128 halfs per row) to workspace
#pragma unroll
        for (int t = 0; t < 8; t++)
#pragma unroll
            for (int r = 0; r < 4; r++) {
                int row = R + q * 4 + r;
                if (row < N) {
                    float v = acc[t][r];
                    __half h = __float2half_rn(v);
                    size_t base = (size_t)row * 256;
                    Hout[base + t * 16 + c] = h;
                    Hout[base + 128 + t * 16 + c] = __float2half_rn(v - __half2float(h));
                }
            }
        return;
    }

    // ---- fused FC ----
    __syncthreads();  // all waves done reading the weight double-buffer
    // H staging (wave-private 8 KB: hi 4 KB | lo 4 KB), XOR-swizzled uint4 index
    unsigned short* hw = (unsigned short*)(smem4 + wave * 512);
#pragma unroll
    for (int t = 0; t < 8; t++)
#pragma unroll
        for (int r = 0; r < 4; r++) {
            int m = q * 4 + r;
            float v = acc[t][r];
            __half h = __float2half_rn(v);
            int j4 = (t * 2 + (c >> 3)) ^ (m & 7);
            int off = m * 128 + j4 * 8 + (c & 7);
            hw[off] = __half_as_ushort(h);
            hw[2048 + off] = __half_as_ushort(__float2half_rn(v - __half2float(h)));
        }
    __syncthreads();  // defensive: make H staging globally visible before frag reads
    uint4 a2h_[4], a2l_[4];
#pragma unroll
    for (int k2 = 0; k2 < 4; k2++) {
        int r4 = (k2 * 4 + q) ^ (c & 7);
        a2h_[k2] = *(const uint4*)(hw + c * 128 + r4 * 8);
        a2l_[k2] = *(const uint4*)(hw + 2048 + c * 128 + r4 * 8);
    }

    f32x4 acc2[8];
#pragma unroll
    for (int t = 0; t < 8; t++) {
        float bv = bias2[t * 16 + c];
#pragma unroll
        for (int r = 0; r < 4; r++) acc2[t][r] = bv;
    }
#pragma unroll
    for (int k2 = 0; k2 < 4; k2++) {
        const uint4* Wh = W2h + (size_t)k2 * 512 + lane;
        const uint4* Wl = W2l + (size_t)k2 * 512 + lane;
        f16x8 ah = __builtin_bit_cast(f16x8, a2h_[k2]);
        f16x8 al = __builtin_bit_cast(f16x8, a2l_[k2]);
#pragma unroll
        for (int t = 0; t < 8; t++) {
            f16x8 bh = __builtin_bit_cast(f16x8, Wh[t * 64]);
            f16x8 bl = __builtin_bit_cast(f16x8, Wl[t * 64]);
            acc2[t] = __builtin_amdgcn_mfma_f32_16x16x32_f16(ah, bh, acc2[t], 0, 0, 0);
            acc2[t] = __builtin_amdgcn_mfma_f32_16x16x32_f16(al, bh, acc2[t], 0, 0, 0);
            acc2[t] = __builtin_amdgcn_mfma_f32_16x16x32_f16(ah, bl, acc2[t], 0, 0, 0);
        }
    }

#pragma unroll
    for (int t = 0; t < 8; t++)
#pragma unroll
        for (int r = 0; r < 4; r++) {
            int row = R + q * 4 + r;
            if (row < N) out[(size_t)row * D + t * 16 + c] = acc2[t][r];
        }
#undef STAGE_W
}

extern "C" void kernel_launch(void* const* d_in, const int* in_sizes, int n_in,
                              void* d_out, int out_size, void* d_ws, size_t ws_size,
                              hipStream_t stream) {
    const float* x   = (const float*)d_in[0];
    const int*   ei  = (const int*)d_in[1];
    const float* W1l = (const float*)d_in[2];
    const float* b1  = (const float*)d_in[3];
    const float* W1r = (const float*)d_in[4];
    const float* W2l = (const float*)d_in[5];
    const float* b2  = (const float*)d_in[6];
    const float* W2r = (const float*)d_in[7];
    const float* Wf  = (const float*)d_in[8];
    const float* bf  = (const float*)d_in[9];
    float* out = (float*)d_out;

    int N = in_sizes[0] / D;
    int E = in_sizes[1] / 2;

    // ws: Xh | Xl (N*D halfs) | H1 (N*256 halfs, interleaved hi|lo) | inv f | rs i | cnt i |
    //     cursor i | bsum[256] i | csr[E] i | pw[5*32768] ush   (~56 MB)
    __half* Xh  = (__half*)d_ws;
    __half* Xl  = Xh + (size_t)N * D;
    __half* H1  = Xl + (size_t)N * D;
    float* inv  = (float*)(H1 + (size_t)N * 256);
    int*   rs     = (int*)(inv + N);
    int*   cnt    = rs + N;
    int*   cursor = cnt + N;
    int*   bsum   = cursor + N;
    int*   csr    = bsum + 256;
    unsigned short* pw = (unsigned short*)(csr + E);
    unsigned short* p1lh = pw + 0 * 32768, *p1ll = p1lh + 16384;
    unsigned short* p1rh = pw + 1 * 32768, *p1rl = p1rh + 16384;
    unsigned short* p2lh = pw + 2 * 32768, *p2ll = p2lh + 16384;
    unsigned short* p2rh = pw + 3 * 32768, *p2rl = p2rh + 16384;
    unsigned short* pfh  = pw + 4 * 32768, *pfl  = pfh + 16384;

    int nb = (N + SCAN_B - 1) / SCAN_B;
    int n8 = N * 16;

    hipMemsetAsync(cnt, 0, (size_t)N * sizeof(int), stream);
    int pro_threads = 10240 + n8 + E;
    prologue_kernel<<<(pro_threads + 255) / 256, 256, 0, stream>>>(
        W1l, W1r, W2l, W2r, Wf, pw, x, Xh, Xl, n8, ei, E, cnt);
    scan_pass1<<<nb, SCAN_B, 0, stream>>>(cnt, rs, bsum, N);
    scan_pass2<<<1, SCAN_B, 0, stream>>>(bsum, nb);
    scan_pass3<<<nb, SCAN_B, 0, stream>>>(rs, cursor, bsum, cnt, inv, N);
    fill_kernel<<<(E + 255) / 256, 256, 0, stream>>>(ei, E, cursor, csr);

    int gemm_blocks = (N + 63) / 64;

    // layer 1: fused gather(Xh) + GEMM(agg | Xh/Xl) -> h1 interleaved in ws
    fused_gemm<1><<<gemm_blocks, 256, 0, stream>>>(
        csr, rs, cnt, inv,
        (const uint4*)Xh, (const uint4*)Xh, (const uint4*)Xl,
        (const uint4*)p1lh, (const uint4*)p1ll, (const uint4*)p1rh, (const uint4*)p1rl, b1,
        nullptr, nullptr, nullptr, nullptr, H1, N);

    // layer 2: fused gather(H1-hi) + GEMM(agg | H1 hi/lo) + fused FC -> fp32 out
    fused_gemm<2><<<gemm_blocks, 256, 0, stream>>>(
        csr, rs, cnt, inv,
        (const uint4*)H1, (const uint4*)H1, (const uint4*)H1 + 16,
        (const uint4*)p2lh, (const uint4*)p2ll, (const uint4*)p2rh, (const uint4*)p2rl, b2,
        (const uint4*)pfh, (const uint4*)pfl, bf, out, nullptr, N);
}

// Round 10
// 274.500 us; speedup vs baseline: 1.0128x; 1.0128x over previous
//
#include <hip/hip_runtime.h>
#include <hip/hip_fp16.h>

#define D 128
#define SCAN_B 256

typedef __attribute__((ext_vector_type(8))) _Float16 f16x8;
typedef __attribute__((ext_vector_type(4))) float f32x4;

typedef __attribute__((address_space(1))) const void gas_t;
typedef __attribute__((address_space(3))) void las_t;

// ---- hierarchical exclusive scan ----
__global__ void scan_pass1(const int* __restrict__ cnt, int* __restrict__ rs,
                           int* __restrict__ bsum, int N) {
    __shared__ int lds[SCAN_B];
    int tid = threadIdx.x;
    int i = blockIdx.x * SCAN_B + tid;
    int v = (i < N) ? cnt[i] : 0;
    lds[tid] = v;
    __syncthreads();
    for (int o = 1; o < SCAN_B; o <<= 1) {
        int t = (tid >= o) ? lds[tid - o] : 0;
        __syncthreads();
        lds[tid] += t;
        __syncthreads();
    }
    if (i < N) rs[i] = lds[tid] - v;
    if (tid == SCAN_B - 1) bsum[blockIdx.x] = lds[tid];
}

__global__ void scan_pass2(int* __restrict__ bsum, int nb) {
    __shared__ int lds[SCAN_B];
    int tid = threadIdx.x;
    int v = (tid < nb) ? bsum[tid] : 0;
    lds[tid] = v;
    __syncthreads();
    for (int o = 1; o < SCAN_B; o <<= 1) {
        int t = (tid >= o) ? lds[tid - o] : 0;
        __syncthreads();
        lds[tid] += t;
        __syncthreads();
    }
    if (tid < nb) bsum[tid] = lds[tid] - v;
}

__global__ void scan_pass3(int* __restrict__ rs, int* __restrict__ cursor,
                           const int* __restrict__ bsum, const int* __restrict__ cnt,
                           float* __restrict__ inv, int N) {
    int i = blockIdx.x * SCAN_B + threadIdx.x;
    if (i < N) {
        int v = rs[i] + bsum[blockIdx.x];
        rs[i] = v;
        cursor[i] = v;
        inv[i] = 1.0f / (float)max(cnt[i], 1);
    }
}

__global__ void fill_kernel(const int* __restrict__ ei, int E,
                            int* __restrict__ cursor, int* __restrict__ csr) {
    int e = blockIdx.x * blockDim.x + threadIdx.x;
    if (e < E) {
        int src = ei[e], dst = ei[E + e];
        int pos = atomicAdd(&cursor[dst], 1);
        csr[pos] = src;
    }
}

// ---- fused prologue: weight pack | fp32->f16 hi/lo cvt | degree count ----
__global__ void prologue_kernel(const float* __restrict__ W1l, const float* __restrict__ W1r,
                                const float* __restrict__ W2l, const float* __restrict__ W2r,
                                const float* __restrict__ Wf, unsigned short* __restrict__ pw,
                                const float* __restrict__ x, __half* __restrict__ xh,
                                __half* __restrict__ xl, int n8,
                                const int* __restrict__ ei, int E, int* __restrict__ cnt) {
    int t = blockIdx.x * blockDim.x + threadIdx.x;
    if (t < 10240) {
        int idx = t;
        int w = idx >> 11;
        int r = idx & 2047;
        int ks = r >> 9;
        int tt = (r >> 6) & 7;
        int lane = r & 63;
        int q = lane >> 4, n = lane & 15;
        const float* W = (w == 0) ? W1l : (w == 1) ? W1r : (w == 2) ? W2l : (w == 3) ? W2r : Wf;
        unsigned short* dh = pw + (size_t)w * 32768;
        unsigned short* dl = dh + 16384;
        int off = ((ks * 8 + tt) * 64 + lane) * 8;
#pragma unroll
        for (int j = 0; j < 8; j++) {
            float v = W[(size_t)(ks * 32 + q * 8 + j) * D + tt * 16 + n];
            __half hb = __float2half_rn(v);
            dh[off + j] = __half_as_ushort(hb);
            dl[off + j] = __half_as_ushort(__float2half_rn(v - __half2float(hb)));
        }
    } else if (t < 10240 + n8) {
        int i = t - 10240;
        const float4* x4 = (const float4*)x;
        float4 a = x4[2 * i], b = x4[2 * i + 1];
        float v[8] = {a.x, a.y, a.z, a.w, b.x, b.y, b.z, b.w};
        uint4 oh, ol;
        __half2* ph = (__half2*)&oh;
        __half2* pl = (__half2*)&ol;
#pragma unroll
        for (int jj = 0; jj < 4; jj++) {
            __half h0 = __float2half_rn(v[2 * jj]);
            __half h1 = __float2half_rn(v[2 * jj + 1]);
            ph[jj] = __halves2half2(h0, h1);
            pl[jj] = __halves2half2(__float2half_rn(v[2 * jj] - __half2float(h0)),
                                    __float2half_rn(v[2 * jj + 1] - __half2float(h1)));
        }
        ((uint4*)xh)[i] = oh;
        ((uint4*)xl)[i] = ol;
    } else {
        int e = t - 10240 - n8;
        if (e < E) atomicAdd(&cnt[ei[E + e]], 1);
    }
}

// ---- gather-mean aggregate: ONE WAVE PER NODE (zero intra-wave divergence) ----
// 64 lanes x 4B (half2) cover the 256B source row in one coalesced access.
// Per-column f32 accumulation in csr order == previous kernel's numerics exactly.
__global__ void aggregate_kernel(const __half* __restrict__ xh, int sstride_dw,
                                 const int* __restrict__ csr,
                                 const int* __restrict__ rs, const int* __restrict__ cnt,
                                 const float* __restrict__ inv,
                                 __half* __restrict__ aggh, __half* __restrict__ aggl, int N) {
    int wid = (blockIdx.x * blockDim.x + threadIdx.x) >> 6;   // node id
    int lane = threadIdx.x & 63;
    if (wid >= N) return;
    int deg = cnt[wid];
    int st = rs[wid];
    const unsigned* src = (const unsigned*)xh;
    float s0 = 0.f, s1 = 0.f;
    int i = 0;
    for (; i + 4 <= deg; i += 4) {
        int n0 = csr[st + i + 0], n1 = csr[st + i + 1];
        int n2 = csr[st + i + 2], n3 = csr[st + i + 3];
        unsigned u0 = src[(size_t)n0 * sstride_dw + lane];
        unsigned u1 = src[(size_t)n1 * sstride_dw + lane];
        unsigned u2 = src[(size_t)n2 * sstride_dw + lane];
        unsigned u3 = src[(size_t)n3 * sstride_dw + lane];
        float2 f0 = __half22float2(*(const __half2*)&u0);
        float2 f1 = __half22float2(*(const __half2*)&u1);
        float2 f2 = __half22float2(*(const __half2*)&u2);
        float2 f3 = __half22float2(*(const __half2*)&u3);
        s0 += f0.x; s1 += f0.y;
        s0 += f1.x; s1 += f1.y;
        s0 += f2.x; s1 += f2.y;
        s0 += f3.x; s1 += f3.y;
    }
    for (; i < deg; i++) {
        int n0 = csr[st + i];
        unsigned u0 = src[(size_t)n0 * sstride_dw + lane];
        float2 f0 = __half22float2(*(const __half2*)&u0);
        s0 += f0.x; s1 += f0.y;
    }
    float iv = inv[wid];
    float v0 = s0 * iv, v1 = s1 * iv;
    __half h0 = __float2half_rn(v0), h1 = __float2half_rn(v1);
    ((__half2*)aggh)[(size_t)wid * 64 + lane] = __halves2half2(h0, h1);
    ((__half2*)aggl)[(size_t)wid * 64 + lane] =
        __halves2half2(__float2half_rn(v0 - __half2float(h0)),
                       __float2half_rn(v1 - __half2float(h1)));
}

// ---- full-row-wave MFMA GEMM, weights staged via global_load_lds double-buffer ----
// (round-6 proven structure, unchanged)
template <int LAYER>
__global__ __launch_bounds__(256) void mfma_gemm(
        const uint4* __restrict__ Agh, const uint4* __restrict__ Agl,  // stride 16 uint4/row
        const uint4* __restrict__ Ah1, const uint4* __restrict__ Al1,  // x (s16) or h1 (s32)
        const uint4* __restrict__ W0h, const uint4* __restrict__ W0l,
        const uint4* __restrict__ W1h, const uint4* __restrict__ W1l,
        const float* __restrict__ bias,
        const uint4* __restrict__ W2h, const uint4* __restrict__ W2l,
        const float* __restrict__ bias2,
        float* out, __half* Hout, int N) {
    __shared__ uint4 smem4[2048];   // 32 KB: W double-buffer; LAYER2 reuses for H staging

    const int tid = threadIdx.x;
    const int lane = tid & 63;
    const int wave = tid >> 6;
    const int c = lane & 15;
    const int q = lane >> 4;
    const int R = blockIdx.x * 64 + wave * 16;
    const int row0 = min(R + c, N - 1);
    const size_t rb16 = (size_t)row0 * 16 + q;
    const size_t rbA1 = (size_t)row0 * (LAYER == 1 ? 16 : 32) + q;

#define STAGE_W(ks_, b_)                                                                   \
    do {                                                                                   \
        const uint4* sh_ = (((ks_) < 4) ? W0h : W1h) + (size_t)((ks_) & 3) * 512;          \
        const uint4* sl_ = (((ks_) < 4) ? W0l : W1l) + (size_t)((ks_) & 3) * 512;          \
        const uint4* s_ = ((wave < 2) ? sh_ : sl_) + ((wave & 1) * 256 + lane);            \
        uint4* d_ = smem4 + (b_) * 1024 + (wave >> 1) * 512 + (wave & 1) * 256;            \
        __builtin_amdgcn_global_load_lds((gas_t*)(s_), (las_t*)(d_), 16, 0, 0);            \
        __builtin_amdgcn_global_load_lds((gas_t*)(s_ + 64), (las_t*)(d_ + 64), 16, 0, 0);  \
        __builtin_amdgcn_global_load_lds((gas_t*)(s_ + 128), (las_t*)(d_ + 128), 16, 0, 0);\
        __builtin_amdgcn_global_load_lds((gas_t*)(s_ + 192), (las_t*)(d_ + 192), 16, 0, 0);\
    } while (0)

#define LOAD_A(ks_, s_)                                                       \
    do {                                                                      \
        if ((ks_) < 4) {                                                      \
            A_h[s_] = Agh[rb16 + (ks_) * 4];                                  \
            A_l[s_] = Agl[rb16 + (ks_) * 4];                                  \
        } else {                                                              \
            A_h[s_] = Ah1[rbA1 + ((ks_) - 4) * 4];                            \
            A_l[s_] = Al1[rbA1 + ((ks_) - 4) * 4];                            \
        }                                                                     \
    } while (0)

    uint4 A_h[2], A_l[2];
    STAGE_W(0, 0);
    STAGE_W(1, 1);
    LOAD_A(0, 0);
    LOAD_A(1, 1);
    asm volatile("s_waitcnt vmcnt(0)" ::: "memory");
    __syncthreads();

    f32x4 acc[8];
#pragma unroll
    for (int t = 0; t < 8; t++)
#pragma unroll
        for (int r = 0; r < 4; r++) acc[t][r] = 0.0f;

#pragma unroll
    for (int ks = 0; ks < 8; ks++) {
        const int b = ks & 1;
        const uint4* wb = smem4 + b * 1024;
        f16x8 ah = __builtin_bit_cast(f16x8, A_h[b]);
        f16x8 al = __builtin_bit_cast(f16x8, A_l[b]);
#pragma unroll
        for (int t = 0; t < 8; t++) {
            f16x8 bh = __builtin_bit_cast(f16x8, wb[t * 64 + lane]);
            f16x8 bl = __builtin_bit_cast(f16x8, wb[512 + t * 64 + lane]);
            acc[t] = __builtin_amdgcn_mfma_f32_16x16x32_f16(ah, bh, acc[t], 0, 0, 0);
            acc[t] = __builtin_amdgcn_mfma_f32_16x16x32_f16(al, bh, acc[t], 0, 0, 0);
            acc[t] = __builtin_amdgcn_mfma_f32_16x16x32_f16(ah, bl, acc[t], 0, 0, 0);
        }
        if (ks < 7) {
            asm volatile("s_waitcnt vmcnt(0)" ::: "memory");  // stage(ks+1)+A(ks+1) landed
            __syncthreads();
            if (ks < 6) {
                STAGE_W(ks + 2, b);  // overwrite just-consumed buffer (all waves past barrier)
                LOAD_A(ks + 2, b);
            }
        }
    }

    // bias + row L2-norm (whole row in this wave: 16-lane shfl reduce) + relu
#pragma unroll
    for (int t = 0; t < 8; t++) {
        float bv = bias[t * 16 + c];
#pragma unroll
        for (int r = 0; r < 4; r++) acc[t][r] += bv;
    }
#pragma unroll
    for (int r = 0; r < 4; r++) {
        float v = 0.0f;
#pragma unroll
        for (int t = 0; t < 8; t++) v += acc[t][r] * acc[t][r];
        v += __shfl_xor(v, 1, 16);
        v += __shfl_xor(v, 2, 16);
        v += __shfl_xor(v, 4, 16);
        v += __shfl_xor(v, 8, 16);
        float rn = 1.0f / fmaxf(sqrtf(v), 1e-12f);
#pragma unroll
        for (int t = 0; t < 8; t++) acc[t][r] = fmaxf(acc[t][r] * rn, 0.0f);
    }

    if (LAYER == 1) {
        // write h1 row-interleaved: per row, halfs [0..127]=hi, [128..255]=lo
#pragma unroll
        for (int t = 0; t < 8; t++)
#pragma unroll
            for (int r = 0; r < 4; r++) {
                int row = R + q * 4 + r;
                if (row < N) {
                    float v = acc[t][r];
                    __half h = __float2half_rn(v);
                    size_t base = (size_t)row * 256;
                    Hout[base + t * 16 + c] = h;
                    Hout[base + 128 + t * 16 + c] = __float2half_rn(v - __half2float(h));
                }
            }
        return;
    }

    // ---- fused FC ----
    __syncthreads();  // all waves done reading the weight double-buffer
    // H staging (wave-private 8 KB: hi 4 KB | lo 4 KB), XOR-swizzled uint4 index
    unsigned short* hw = (unsigned short*)(smem4 + wave * 512);
#pragma unroll
    for (int t = 0; t < 8; t++)
#pragma unroll
        for (int r = 0; r < 4; r++) {
            int m = q * 4 + r;
            float v = acc[t][r];
            __half h = __float2half_rn(v);
            int j4 = (t * 2 + (c >> 3)) ^ (m & 7);
            int off = m * 128 + j4 * 8 + (c & 7);
            hw[off] = __half_as_ushort(h);
            hw[2048 + off] = __half_as_ushort(__float2half_rn(v - __half2float(h)));
        }
    // wave-private RAW: compiler orders via lgkmcnt; no barrier needed
    uint4 a2h_[4], a2l_[4];
#pragma unroll
    for (int k2 = 0; k2 < 4; k2++) {
        int r4 = (k2 * 4 + q) ^ (c & 7);
        a2h_[k2] = *(const uint4*)(hw + c * 128 + r4 * 8);
        a2l_[k2] = *(const uint4*)(hw + 2048 + c * 128 + r4 * 8);
    }

    f32x4 acc2[8];
#pragma unroll
    for (int t = 0; t < 8; t++) {
        float bv = bias2[t * 16 + c];
#pragma unroll
        for (int r = 0; r < 4; r++) acc2[t][r] = bv;
    }
#pragma unroll
    for (int k2 = 0; k2 < 4; k2++) {
        const uint4* Wh = W2h + (size_t)k2 * 512 + lane;
        const uint4* Wl = W2l + (size_t)k2 * 512 + lane;
        f16x8 ah = __builtin_bit_cast(f16x8, a2h_[k2]);
        f16x8 al = __builtin_bit_cast(f16x8, a2l_[k2]);
#pragma unroll
        for (int t = 0; t < 8; t++) {
            f16x8 bh = __builtin_bit_cast(f16x8, Wh[t * 64]);
            f16x8 bl = __builtin_bit_cast(f16x8, Wl[t * 64]);
            acc2[t] = __builtin_amdgcn_mfma_f32_16x16x32_f16(ah, bh, acc2[t], 0, 0, 0);
            acc2[t] = __builtin_amdgcn_mfma_f32_16x16x32_f16(al, bh, acc2[t], 0, 0, 0);
            acc2[t] = __builtin_amdgcn_mfma_f32_16x16x32_f16(ah, bl, acc2[t], 0, 0, 0);
        }
    }

#pragma unroll
    for (int t = 0; t < 8; t++)
#pragma unroll
        for (int r = 0; r < 4; r++) {
            int row = R + q * 4 + r;
            if (row < N) out[(size_t)row * D + t * 16 + c] = acc2[t][r];
        }
#undef STAGE_W
#undef LOAD_A
}

extern "C" void kernel_launch(void* const* d_in, const int* in_sizes, int n_in,
                              void* d_out, int out_size, void* d_ws, size_t ws_size,
                              hipStream_t stream) {
    const float* x   = (const float*)d_in[0];
    const int*   ei  = (const int*)d_in[1];
    const float* W1l = (const float*)d_in[2];
    const float* b1  = (const float*)d_in[3];
    const float* W1r = (const float*)d_in[4];
    const float* W2l = (const float*)d_in[5];
    const float* b2  = (const float*)d_in[6];
    const float* W2r = (const float*)d_in[7];
    const float* Wf  = (const float*)d_in[8];
    const float* bf  = (const float*)d_in[9];
    float* out = (float*)d_out;

    int N = in_sizes[0] / D;
    int E = in_sizes[1] / 2;

    // ws: Agh | Agl | Xh | Xl (N*D halfs each) | inv f | rs i | cnt i | cursor i |
    //     bsum[256] i | csr[E] i | pw[5*32768] ush   (~55 MB)
    // h1 (f16 hi/lo, row-interleaved) lives in d_out between the two GEMMs.
    __half* Agh = (__half*)d_ws;
    __half* Agl = Agh + (size_t)N * D;
    __half* Xh  = Agl + (size_t)N * D;
    __half* Xl  = Xh + (size_t)N * D;
    float* inv  = (float*)(Xl + (size_t)N * D);
    int*   rs     = (int*)(inv + N);
    int*   cnt    = rs + N;
    int*   cursor = cnt + N;
    int*   bsum   = cursor + N;
    int*   csr    = bsum + 256;
    unsigned short* pw = (unsigned short*)(csr + E);
    unsigned short* p1lh = pw + 0 * 32768, *p1ll = p1lh + 16384;
    unsigned short* p1rh = pw + 1 * 32768, *p1rl = p1rh + 16384;
    unsigned short* p2lh = pw + 2 * 32768, *p2ll = p2lh + 16384;
    unsigned short* p2rh = pw + 3 * 32768, *p2rl = p2rh + 16384;
    unsigned short* pfh  = pw + 4 * 32768, *pfl  = pfh + 16384;

    __half* H1 = (__half*)d_out;  // interleaved h1: row*256 halfs (hi 128 | lo 128)

    int nb = (N + SCAN_B - 1) / SCAN_B;
    int n8 = N * 16;

    hipMemsetAsync(cnt, 0, (size_t)N * sizeof(int), stream);
    int pro_threads = 10240 + n8 + E;
    prologue_kernel<<<(pro_threads + 255) / 256, 256, 0, stream>>>(
        W1l, W1r, W2l, W2r, Wf, pw, x, Xh, Xl, n8, ei, E, cnt);
    scan_pass1<<<nb, SCAN_B, 0, stream>>>(cnt, rs, bsum, N);
    scan_pass2<<<1, SCAN_B, 0, stream>>>(bsum, nb);
    scan_pass3<<<nb, SCAN_B, 0, stream>>>(rs, cursor, bsum, cnt, inv, N);
    fill_kernel<<<(E + 255) / 256, 256, 0, stream>>>(ei, E, cursor, csr);

    int agg_blocks = (N + 3) / 4;          // one wave per node, 4 waves/block
    int gemm_blocks = (N + 63) / 64;

    // layer 1: agg from Xh (row stride 64 dwords); GEMM reads (agg | Xh/Xl) -> h1 in d_out
    aggregate_kernel<<<agg_blocks, 256, 0, stream>>>(Xh, 64, csr, rs, cnt, inv, Agh, Agl, N);
    mfma_gemm<1><<<gemm_blocks, 256, 0, stream>>>(
        (const uint4*)Agh, (const uint4*)Agl, (const uint4*)Xh, (const uint4*)Xl,
        (const uint4*)p1lh, (const uint4*)p1ll, (const uint4*)p1rh, (const uint4*)p1rl, b1,
        nullptr, nullptr, nullptr, nullptr, H1, N);

    // layer 2: agg from h1-hi (row stride 128 dwords); GEMM + fused FC, fp32 out in place
    aggregate_kernel<<<agg_blocks, 256, 0, stream>>>(H1, 128, csr, rs, cnt, inv, Agh, Agl, N);
    mfma_gemm<2><<<gemm_blocks, 256, 0, stream>>>(
        (const uint4*)Agh, (const uint4*)Agl,
        (const uint4*)d_out, (const uint4*)d_out + 16,
        (const uint4*)p2lh, (const uint4*)p2ll, (const uint4*)p2rh, (const uint4*)p2rl, b2,
        (const uint4*)pfh, (const uint4*)pfl, bf, out, nullptr, N);
}

// Round 11
// 260.342 us; speedup vs baseline: 1.0678x; 1.0544x over previous
//
#include <hip/hip_runtime.h>
#include <hip/hip_fp16.h>

#define D 128
#define SCAN_B 256

typedef __attribute__((ext_vector_type(8))) _Float16 f16x8;
typedef __attribute__((ext_vector_type(4))) float f32x4;

typedef __attribute__((address_space(1))) const void gas_t;
typedef __attribute__((address_space(3))) void las_t;

// ---- hierarchical exclusive scan (2 kernels: pass1 + fused pass3) ----
__global__ void scan_pass1(const int* __restrict__ cnt, int* __restrict__ rs,
                           int* __restrict__ bsum, int N) {
    __shared__ int lds[SCAN_B];
    int tid = threadIdx.x;
    int i = blockIdx.x * SCAN_B + tid;
    int v = (i < N) ? cnt[i] : 0;
    lds[tid] = v;
    __syncthreads();
    for (int o = 1; o < SCAN_B; o <<= 1) {
        int t = (tid >= o) ? lds[tid - o] : 0;
        __syncthreads();
        lds[tid] += t;
        __syncthreads();
    }
    if (i < N) rs[i] = lds[tid] - v;
    if (tid == SCAN_B - 1) bsum[blockIdx.x] = lds[tid];
}

// fused: each block redundantly scans bsum (nb <= 256) to get its own offset
__global__ void scan_pass3(int* __restrict__ rs, int* __restrict__ cursor,
                           const int* __restrict__ bsum, const int* __restrict__ cnt,
                           float* __restrict__ inv, int N, int nb) {
    __shared__ int lds[SCAN_B];
    int tid = threadIdx.x;
    int v = (tid < nb) ? bsum[tid] : 0;
    lds[tid] = v;
    __syncthreads();
    for (int o = 1; o < SCAN_B; o <<= 1) {
        int t = (tid >= o) ? lds[tid - o] : 0;
        __syncthreads();
        lds[tid] += t;
        __syncthreads();
    }
    int boff = (blockIdx.x == 0) ? 0 : lds[blockIdx.x - 1];
    int i = blockIdx.x * SCAN_B + tid;
    if (i < N) {
        int vv = rs[i] + boff;
        rs[i] = vv;
        cursor[i] = vv;
        inv[i] = 1.0f / (float)max(cnt[i], 1);
    }
}

__global__ void fill_kernel(const int* __restrict__ ei, int E,
                            int* __restrict__ cursor, int* __restrict__ csr) {
    int e = blockIdx.x * blockDim.x + threadIdx.x;
    if (e < E) {
        int src = ei[e], dst = ei[E + e];
        int pos = atomicAdd(&cursor[dst], 1);
        csr[pos] = src;
    }
}

// ---- fused prologue: weight pack | fp32->f16 hi/lo cvt | degree count ----
__global__ void prologue_kernel(const float* __restrict__ W1l, const float* __restrict__ W1r,
                                const float* __restrict__ W2l, const float* __restrict__ W2r,
                                const float* __restrict__ Wf, unsigned short* __restrict__ pw,
                                const float* __restrict__ x, __half* __restrict__ xh,
                                __half* __restrict__ xl, int n8,
                                const int* __restrict__ ei, int E, int* __restrict__ cnt) {
    int t = blockIdx.x * blockDim.x + threadIdx.x;
    if (t < 10240) {
        int idx = t;
        int w = idx >> 11;
        int r = idx & 2047;
        int ks = r >> 9;
        int tt = (r >> 6) & 7;
        int lane = r & 63;
        int q = lane >> 4, n = lane & 15;
        const float* W = (w == 0) ? W1l : (w == 1) ? W1r : (w == 2) ? W2l : (w == 3) ? W2r : Wf;
        unsigned short* dh = pw + (size_t)w * 32768;
        unsigned short* dl = dh + 16384;
        int off = ((ks * 8 + tt) * 64 + lane) * 8;
#pragma unroll
        for (int j = 0; j < 8; j++) {
            float v = W[(size_t)(ks * 32 + q * 8 + j) * D + tt * 16 + n];
            __half hb = __float2half_rn(v);
            dh[off + j] = __half_as_ushort(hb);
            dl[off + j] = __half_as_ushort(__float2half_rn(v - __half2float(hb)));
        }
    } else if (t < 10240 + n8) {
        int i = t - 10240;
        const float4* x4 = (const float4*)x;
        float4 a = x4[2 * i], b = x4[2 * i + 1];
        float v[8] = {a.x, a.y, a.z, a.w, b.x, b.y, b.z, b.w};
        uint4 oh, ol;
        __half2* ph = (__half2*)&oh;
        __half2* pl = (__half2*)&ol;
#pragma unroll
        for (int jj = 0; jj < 4; jj++) {
            __half h0 = __float2half_rn(v[2 * jj]);
            __half h1 = __float2half_rn(v[2 * jj + 1]);
            ph[jj] = __halves2half2(h0, h1);
            pl[jj] = __halves2half2(__float2half_rn(v[2 * jj] - __half2float(h0)),
                                    __float2half_rn(v[2 * jj + 1] - __half2float(h1)));
        }
        ((uint4*)xh)[i] = oh;
        ((uint4*)xl)[i] = ol;
    } else {
        int e = t - 10240 - n8;
        if (e < E) atomicAdd(&cnt[ei[E + e]], 1);
    }
}

__device__ __forceinline__ void acc8(uint4 v, float* s) {
    const __half2* h = reinterpret_cast<const __half2*>(&v);
    float2 f0 = __half22float2(h[0]);
    float2 f1 = __half22float2(h[1]);
    float2 f2 = __half22float2(h[2]);
    float2 f3 = __half22float2(h[3]);
    s[0] += f0.x; s[1] += f0.y; s[2] += f1.x; s[3] += f1.y;
    s[4] += f2.x; s[5] += f2.y; s[6] += f3.x; s[7] += f3.y;
}

// ---- gather-mean aggregate: 16 lanes/node, 8 cols/lane (round-6 proven shape) ----
__global__ void aggregate_kernel(const __half* __restrict__ xh, int sstride,
                                 const int* __restrict__ csr,
                                 const int* __restrict__ rs, const int* __restrict__ cnt,
                                 const float* __restrict__ inv,
                                 __half* __restrict__ aggh, __half* __restrict__ aggl, int N) {
    int t = blockIdx.x * blockDim.x + threadIdx.x;
    int node = t >> 4;
    int c = t & 15;
    if (node >= N) return;
    int deg = cnt[node];
    int st = rs[node];
    const uint4* x4 = (const uint4*)xh;
    float s[8] = {0.f, 0.f, 0.f, 0.f, 0.f, 0.f, 0.f, 0.f};
    int i = 0;
    for (; i + 4 <= deg; i += 4) {
        int n0 = csr[st + i + 0], n1 = csr[st + i + 1];
        int n2 = csr[st + i + 2], n3 = csr[st + i + 3];
        uint4 v0 = x4[(size_t)n0 * sstride + c];
        uint4 v1 = x4[(size_t)n1 * sstride + c];
        uint4 v2 = x4[(size_t)n2 * sstride + c];
        uint4 v3 = x4[(size_t)n3 * sstride + c];
        acc8(v0, s); acc8(v1, s); acc8(v2, s); acc8(v3, s);
    }
    for (; i < deg; i++) {
        int n0 = csr[st + i];
        uint4 v0 = x4[(size_t)n0 * sstride + c];
        acc8(v0, s);
    }
    float iv = inv[node];
    uint4 oh, ol;
    __half2* ph = (__half2*)&oh;
    __half2* pl = (__half2*)&ol;
#pragma unroll
    for (int jj = 0; jj < 4; jj++) {
        float v0 = s[2 * jj] * iv, v1 = s[2 * jj + 1] * iv;
        __half h0 = __float2half_rn(v0), h1 = __float2half_rn(v1);
        ph[jj] = __halves2half2(h0, h1);
        pl[jj] = __halves2half2(__float2half_rn(v0 - __half2float(h0)),
                                __float2half_rn(v1 - __half2float(h1)));
    }
    ((uint4*)aggh)[(size_t)node * 16 + c] = oh;
    ((uint4*)aggl)[(size_t)node * 16 + c] = ol;
}

// ---- full-row-wave MFMA GEMM, pair-granular LDS weight staging ----
// block = 4 waves x 16 rows. grid = ceil(N/64). K=256 in 8 steps, staged as 4 pairs
// of 32KB LDS buffers (2 buffers, 64KB total): 3 vmcnt+barrier drains instead of 7.
// LAYER2: fused FC with its OWN global_load_lds weight double-buffer (16KB steps).
template <int LAYER>
__global__ __launch_bounds__(256) void mfma_gemm(
        const uint4* __restrict__ Agh, const uint4* __restrict__ Agl,  // stride 16 uint4/row
        const uint4* __restrict__ Ah1, const uint4* __restrict__ Al1,  // x (s16) or h1 (s32)
        const uint4* __restrict__ W0h, const uint4* __restrict__ W0l,
        const uint4* __restrict__ W1h, const uint4* __restrict__ W1l,
        const float* __restrict__ bias,
        const uint4* __restrict__ W2h, const uint4* __restrict__ W2l,
        const float* __restrict__ bias2,
        float* out, __half* Hout, int N) {
    __shared__ uint4 smem4[4096];   // 64 KB: 2 x 32KB W pair-buffers; LAYER2 FC reuses

    const int tid = threadIdx.x;
    const int lane = tid & 63;
    const int wave = tid >> 6;
    const int c = lane & 15;
    const int q = lane >> 4;
    const int R = blockIdx.x * 64 + wave * 16;
    const int row0 = min(R + c, N - 1);
    const size_t rb16 = (size_t)row0 * 16 + q;
    const size_t rbA1 = (size_t)row0 * (LAYER == 1 ? 16 : 32) + q;

// stage main-W step ks_ into uint4 offset o_ (hi at o_, lo at o_+512)
#define STAGE_W(ks_, o_)                                                                   \
    do {                                                                                   \
        const uint4* sh_ = (((ks_) < 4) ? W0h : W1h) + (size_t)((ks_) & 3) * 512;          \
        const uint4* sl_ = (((ks_) < 4) ? W0l : W1l) + (size_t)((ks_) & 3) * 512;          \
        const uint4* s_ = ((wave < 2) ? sh_ : sl_) + ((wave & 1) * 256 + lane);            \
        uint4* d_ = smem4 + (o_) + (wave >> 1) * 512 + (wave & 1) * 256;                   \
        __builtin_amdgcn_global_load_lds((gas_t*)(s_), (las_t*)(d_), 16, 0, 0);            \
        __builtin_amdgcn_global_load_lds((gas_t*)(s_ + 64), (las_t*)(d_ + 64), 16, 0, 0);  \
        __builtin_amdgcn_global_load_lds((gas_t*)(s_ + 128), (las_t*)(d_ + 128), 16, 0, 0);\
        __builtin_amdgcn_global_load_lds((gas_t*)(s_ + 192), (las_t*)(d_ + 192), 16, 0, 0);\
    } while (0)

#define LOAD_A(ks_, s_)                                                       \
    do {                                                                      \
        if ((ks_) < 4) {                                                      \
            A_h[s_] = Agh[rb16 + (ks_) * 4];                                  \
            A_l[s_] = Agl[rb16 + (ks_) * 4];                                  \
        } else {                                                              \
            A_h[s_] = Ah1[rbA1 + ((ks_) - 4) * 4];                            \
            A_l[s_] = Al1[rbA1 + ((ks_) - 4) * 4];                            \
        }                                                                     \
    } while (0)

    uint4 A_h[4], A_l[4];
    STAGE_W(0, 0);
    STAGE_W(1, 1024);
    STAGE_W(2, 2048);
    STAGE_W(3, 3072);
    LOAD_A(0, 0);
    LOAD_A(1, 1);
    LOAD_A(2, 2);
    LOAD_A(3, 3);
    asm volatile("s_waitcnt vmcnt(0)" ::: "memory");
    __syncthreads();

    f32x4 acc[8];
#pragma unroll
    for (int t = 0; t < 8; t++)
#pragma unroll
        for (int r = 0; r < 4; r++) acc[t][r] = 0.0f;

#pragma unroll
    for (int kp = 0; kp < 4; kp++) {
        const int b = kp & 1;
#pragma unroll
        for (int s = 0; s < 2; s++) {
            const uint4* wb = smem4 + b * 2048 + s * 1024;
            f16x8 ah = __builtin_bit_cast(f16x8, A_h[b * 2 + s]);
            f16x8 al = __builtin_bit_cast(f16x8, A_l[b * 2 + s]);
#pragma unroll
            for (int t = 0; t < 8; t++) {
                f16x8 bh = __builtin_bit_cast(f16x8, wb[t * 64 + lane]);
                f16x8 bl = __builtin_bit_cast(f16x8, wb[512 + t * 64 + lane]);
                acc[t] = __builtin_amdgcn_mfma_f32_16x16x32_f16(ah, bh, acc[t], 0, 0, 0);
                acc[t] = __builtin_amdgcn_mfma_f32_16x16x32_f16(al, bh, acc[t], 0, 0, 0);
                acc[t] = __builtin_amdgcn_mfma_f32_16x16x32_f16(ah, bl, acc[t], 0, 0, 0);
            }
        }
        if (kp < 3) {
            asm volatile("s_waitcnt vmcnt(0)" ::: "memory");  // pair kp+1 landed
            __syncthreads();
            if (kp < 2) {
                STAGE_W(2 * kp + 4, b * 2048);        // overwrite just-consumed pair buffer
                STAGE_W(2 * kp + 5, b * 2048 + 1024);
                LOAD_A(2 * kp + 4, b * 2 + 0);
                LOAD_A(2 * kp + 5, b * 2 + 1);
            }
        }
    }

    // bias + row L2-norm (whole row in this wave: 16-lane shfl reduce) + relu
#pragma unroll
    for (int t = 0; t < 8; t++) {
        float bv = bias[t * 16 + c];
#pragma unroll
        for (int r = 0; r < 4; r++) acc[t][r] += bv;
    }
#pragma unroll
    for (int r = 0; r < 4; r++) {
        float v = 0.0f;
#pragma unroll
        for (int t = 0; t < 8; t++) v += acc[t][r] * acc[t][r];
        v += __shfl_xor(v, 1, 16);
        v += __shfl_xor(v, 2, 16);
        v += __shfl_xor(v, 4, 16);
        v += __shfl_xor(v, 8, 16);
        float rn = 1.0f / fmaxf(sqrtf(v), 1e-12f);
#pragma unroll
        for (int t = 0; t < 8; t++) acc[t][r] = fmaxf(acc[t][r] * rn, 0.0f);
    }

    if (LAYER == 1) {
        // write h1 row-interleaved: per row, halfs [0..127]=hi, [128..255]=lo
#pragma unroll
        for (int t = 0; t < 8; t++)
#pragma unroll
            for (int r = 0; r < 4; r++) {
                int row = R + q * 4 + r;
                if (row < N) {
                    float v = acc[t][r];
                    __half h = __float2half_rn(v);
                    size_t base = (size_t)row * 256;
                    Hout[base + t * 16 + c] = h;
                    Hout[base + 128 + t * 16 + c] = __float2half_rn(v - __half2float(h));
                }
            }
        return;
    }

    // ---- fused FC with LDS-staged weights ----
    __syncthreads();  // all waves done reading main W buffers

// stage FC step k2_ (hi 512 from W2h, lo 512 from W2l) into smem4 + b_*1024
#define STAGE_F(k2_, b_)                                                                   \
    do {                                                                                   \
        const uint4* s_ = ((wave < 2) ? W2h : W2l) + (size_t)(k2_) * 512 +                 \
                          (wave & 1) * 256 + lane;                                         \
        uint4* d_ = smem4 + (b_) * 1024 + (wave >> 1) * 512 + (wave & 1) * 256;            \
        __builtin_amdgcn_global_load_lds((gas_t*)(s_), (las_t*)(d_), 16, 0, 0);            \
        __builtin_amdgcn_global_load_lds((gas_t*)(s_ + 64), (las_t*)(d_ + 64), 16, 0, 0);  \
        __builtin_amdgcn_global_load_lds((gas_t*)(s_ + 128), (las_t*)(d_ + 128), 16, 0, 0);\
        __builtin_amdgcn_global_load_lds((gas_t*)(s_ + 192), (las_t*)(d_ + 192), 16, 0, 0);\
    } while (0)

    STAGE_F(0, 0);   // async into [0..1023] (disjoint from H region below)
    STAGE_F(1, 1);   // async into [1024..2047]

    // H staging (wave-private 8 KB in upper half: hi 4 KB | lo 4 KB), XOR-swizzled
    unsigned short* hw = (unsigned short*)(smem4 + 2048 + wave * 512);
#pragma unroll
    for (int t = 0; t < 8; t++)
#pragma unroll
        for (int r = 0; r < 4; r++) {
            int m = q * 4 + r;
            float v = acc[t][r];
            __half h = __float2half_rn(v);
            int j4 = (t * 2 + (c >> 3)) ^ (m & 7);
            int off = m * 128 + j4 * 8 + (c & 7);
            hw[off] = __half_as_ushort(h);
            hw[2048 + off] = __half_as_ushort(__float2half_rn(v - __half2float(h)));
        }
    // wave-private RAW: compiler orders via lgkmcnt (round-6-proven)
    uint4 a2h_[4], a2l_[4];
#pragma unroll
    for (int k2 = 0; k2 < 4; k2++) {
        int r4 = (k2 * 4 + q) ^ (c & 7);
        a2h_[k2] = *(const uint4*)(hw + c * 128 + r4 * 8);
        a2l_[k2] = *(const uint4*)(hw + 2048 + c * 128 + r4 * 8);
    }

    asm volatile("s_waitcnt vmcnt(0)" ::: "memory");  // FC W steps 0,1 landed
    __syncthreads();

    f32x4 acc2[8];
#pragma unroll
    for (int t = 0; t < 8; t++) {
        float bv = bias2[t * 16 + c];
#pragma unroll
        for (int r = 0; r < 4; r++) acc2[t][r] = bv;
    }
#pragma unroll
    for (int k2 = 0; k2 < 4; k2++) {
        const int b = k2 & 1;
        const uint4* wb2 = smem4 + b * 1024;
        f16x8 ah = __builtin_bit_cast(f16x8, a2h_[k2]);
        f16x8 al = __builtin_bit_cast(f16x8, a2l_[k2]);
#pragma unroll
        for (int t = 0; t < 8; t++) {
            f16x8 bh = __builtin_bit_cast(f16x8, wb2[t * 64 + lane]);
            f16x8 bl = __builtin_bit_cast(f16x8, wb2[512 + t * 64 + lane]);
            acc2[t] = __builtin_amdgcn_mfma_f32_16x16x32_f16(ah, bh, acc2[t], 0, 0, 0);
            acc2[t] = __builtin_amdgcn_mfma_f32_16x16x32_f16(al, bh, acc2[t], 0, 0, 0);
            acc2[t] = __builtin_amdgcn_mfma_f32_16x16x32_f16(ah, bl, acc2[t], 0, 0, 0);
        }
        if (k2 < 3) {
            asm volatile("s_waitcnt vmcnt(0)" ::: "memory");
            __syncthreads();
            if (k2 < 2) STAGE_F(k2 + 2, b);   // overwrite just-consumed FC buffer
        }
    }

#pragma unroll
    for (int t = 0; t < 8; t++)
#pragma unroll
        for (int r = 0; r < 4; r++) {
            int row = R + q * 4 + r;
            if (row < N) out[(size_t)row * D + t * 16 + c] = acc2[t][r];
        }
#undef STAGE_W
#undef STAGE_F
#undef LOAD_A
}

extern "C" void kernel_launch(void* const* d_in, const int* in_sizes, int n_in,
                              void* d_out, int out_size, void* d_ws, size_t ws_size,
                              hipStream_t stream) {
    const float* x   = (const float*)d_in[0];
    const int*   ei  = (const int*)d_in[1];
    const float* W1l = (const float*)d_in[2];
    const float* b1  = (const float*)d_in[3];
    const float* W1r = (const float*)d_in[4];
    const float* W2l = (const float*)d_in[5];
    const float* b2  = (const float*)d_in[6];
    const float* W2r = (const float*)d_in[7];
    const float* Wf  = (const float*)d_in[8];
    const float* bf  = (const float*)d_in[9];
    float* out = (float*)d_out;

    int N = in_sizes[0] / D;
    int E = in_sizes[1] / 2;

    // ws: Agh | Agl | Xh | Xl (N*D halfs each) | inv f | rs i | cnt i | cursor i |
    //     bsum[256] i | csr[E] i | pw[5*32768] ush   (~55 MB)
    // h1 (f16 hi/lo, row-interleaved) lives in d_out between the two GEMMs.
    __half* Agh = (__half*)d_ws;
    __half* Agl = Agh + (size_t)N * D;
    __half* Xh  = Agl + (size_t)N * D;
    __half* Xl  = Xh + (size_t)N * D;
    float* inv  = (float*)(Xl + (size_t)N * D);
    int*   rs     = (int*)(inv + N);
    int*   cnt    = rs + N;
    int*   cursor = cnt + N;
    int*   bsum   = cursor + N;
    int*   csr    = bsum + 256;
    unsigned short* pw = (unsigned short*)(csr + E);
    unsigned short* p1lh = pw + 0 * 32768, *p1ll = p1lh + 16384;
    unsigned short* p1rh = pw + 1 * 32768, *p1rl = p1rh + 16384;
    unsigned short* p2lh = pw + 2 * 32768, *p2ll = p2lh + 16384;
    unsigned short* p2rh = pw + 3 * 32768, *p2rl = p2rh + 16384;
    unsigned short* pfh  = pw + 4 * 32768, *pfl  = pfh + 16384;

    __half* H1 = (__half*)d_out;  // interleaved h1: row*256 halfs (hi 128 | lo 128)

    int nb = (N + SCAN_B - 1) / SCAN_B;   // 196 for N=50000 (must be <= 256)
    int n8 = N * 16;

    hipMemsetAsync(cnt, 0, (size_t)N * sizeof(int), stream);
    int pro_threads = 10240 + n8 + E;
    prologue_kernel<<<(pro_threads + 255) / 256, 256, 0, stream>>>(
        W1l, W1r, W2l, W2r, Wf, pw, x, Xh, Xl, n8, ei, E, cnt);
    scan_pass1<<<nb, SCAN_B, 0, stream>>>(cnt, rs, bsum, N);
    scan_pass3<<<nb, SCAN_B, 0, stream>>>(rs, cursor, bsum, cnt, inv, N, nb);
    fill_kernel<<<(E + 255) / 256, 256, 0, stream>>>(ei, E, cursor, csr);

    int agg_blocks = (N * 16 + 255) / 256;   // 16 lanes/node (round-6 proven)
    int gemm_blocks = (N + 63) / 64;

    // layer 1: agg from Xh; GEMM reads (agg | Xh/Xl) -> h1 interleaved in d_out
    aggregate_kernel<<<agg_blocks, 256, 0, stream>>>(Xh, 16, csr, rs, cnt, inv, Agh, Agl, N);
    mfma_gemm<1><<<gemm_blocks, 256, 0, stream>>>(
        (const uint4*)Agh, (const uint4*)Agl, (const uint4*)Xh, (const uint4*)Xl,
        (const uint4*)p1lh, (const uint4*)p1ll, (const uint4*)p1rh, (const uint4*)p1rl, b1,
        nullptr, nullptr, nullptr, nullptr, H1, N);

    // layer 2: agg from h1-hi (stride 32 uint4); GEMM + fused FC, fp32 out in place
    aggregate_kernel<<<agg_blocks, 256, 0, stream>>>(H1, 32, csr, rs, cnt, inv, Agh, Agl, N);
    mfma_gemm<2><<<gemm_blocks, 256, 0, stream>>>(
        (const uint4*)Agh, (const uint4*)Agl,
        (const uint4*)d_out, (const uint4*)d_out + 16,
        (const uint4*)p2lh, (const uint4*)p2ll, (const uint4*)p2rh, (const uint4*)p2rl, b2,
        (const uint4*)pfh, (const uint4*)pfl, bf, out, nullptr, N);
}